// Round 10
// baseline (183.643 us; speedup 1.0000x reference)
//
#include <hip/hip_runtime.h>
#include <hip/hip_bf16.h>
#include <math.h>

#define BH   32
#define NH   16
#define MM   1024
#define DD   64
#define PP   1024
#define SPAN 1024

typedef unsigned short ushort_t;
typedef __attribute__((ext_vector_type(8))) short  short8;
typedef __attribute__((ext_vector_type(4))) float  f32x4;

#define MFMA(a,b,c) __builtin_amdgcn_mfma_f32_16x16x32_bf16(a,b,c,0,0,0)

#if __has_builtin(__builtin_amdgcn_exp2f)
#define EXP2(x) __builtin_amdgcn_exp2f(x)
#else
#define EXP2(x) __expf((x) * 0.6931471805599453f)
#endif

// exp(a*0.125) = exp2(a * 0.125*log2(e))
#define ATTN_SC 0.18033688011111603f
#define LOG2E   1.4426950408889634f

// ws layout (bytes):
//   [0, 4 MB)        K/V bf16 fragment blobs. Chunk blob (h,c) = 8192 ushorts (16 KB)
//   [4 MB, +128 KB)  per-row s_pers (32768 floats)
//   [4.125 MB, +2KB) per-unit flags (512 ints)
#define WS_SP_OFF   (4194304ull)
#define WS_FLAG_OFF (4325376ull)
#define WS_NEED     (4327424ull)

__device__ __forceinline__ ushort_t f2bf(float x) {
    __hip_bfloat16 b = __float2bfloat16(x);
    return __builtin_bit_cast(unsigned short, b);
}
__device__ __forceinline__ float bf2f(ushort_t u) {
    __hip_bfloat16 b = __builtin_bit_cast(__hip_bfloat16, u);
    return __bfloat162float(b);
}

// ---------------- pre-kernel: bf16 K/V fragment packing (K scaled by log2e) ----------------
__launch_bounds__(256)
__global__ void pm_pre(const float* __restrict__ key,
                       const float* __restrict__ val,
                       ushort_t* __restrict__ wsKV)
{
    int bi = blockIdx.x, t = threadIdx.x;
    if (bi < 512) {
        int id = bi * 256 + t;                 // 131072
        int l  = id & 63;
        int ks = (id >> 6) & 1;
        int pb = (id >> 7) & 3;
        int c  = (id >> 9) & 15;
        int h  = (id >> 13) & 15;
        int p     = c * 64 + pb * 16 + (l & 15);
        int dbase = ks * 32 + (l >> 4) * 8;
        size_t fo = (size_t)(h * 16 + c) * 8192 + (size_t)(pb * 2 + ks) * 512 + (size_t)l * 8;
#pragma unroll
        for (int e = 0; e < 8; ++e)
            wsKV[fo + e] = f2bf(key[(size_t)(h * 64 + dbase + e) * PP + p] * LOG2E);
    } else {
        int id = (bi - 512) * 256 + t;         // 131072
        int l   = id & 63;
        int db  = (id >> 6) & 3;
        int ks2 = (id >> 8) & 1;
        int c   = (id >> 9) & 15;
        int h   = (id >> 13) & 15;
        int d = db * 16 + (l & 15);
        size_t fo = (size_t)(h * 16 + c) * 8192 + 4096 + (size_t)(ks2 * 4 + db) * 512 + (size_t)l * 8;
#pragma unroll
        for (int e = 0; e < 8; ++e) {
            int p = c * 64 + ks2 * 32 + ((l >> 4) * 4) + (e & 3) + 16 * (e >> 2);
            wsKV[fo + e] = f2bf(val[(size_t)(h * PP + p) * DD + d]);
        }
    }
}

// -------- pipelined kernel: flash producer blocks + norm consumer blocks, flag handshake --------
// role = (bi>>3)&1 so each XCD (bi%8) hosts a 50/50 mix. unit = ((bi>>4)<<3)|(bi&7).
// Flash blocks NEVER wait -> resident flash blocks always retire -> progress guaranteed.
__launch_bounds__(256)
__global__ void pm_pipe(const float* __restrict__ q,
                        const float* __restrict__ attn,
                        const ushort_t* __restrict__ wsKV,
                        float* __restrict__ ws_sp,
                        int*   __restrict__ flags,
                        float* __restrict__ attn_out,
                        float* __restrict__ out)
{
    __shared__ ushort_t kvbuf[2][8192];   // 32 KB (flash role); sizes occupancy to 4 blocks/CU
    __shared__ float sa[64];
    __shared__ float iZ[64];

    const int t  = threadIdx.x;
    const int w  = t >> 6;
    const int l  = t & 63;
    const int bi = blockIdx.x;
    const int hi = l >> 4;
    const int lo = l & 15;

    const int role = (bi >> 3) & 1;
    const int unit = ((bi >> 4) << 3) | (bi & 7);   // 0..511
    const int bh   = unit & 31;
    const int tile = unit >> 5;
    const size_t rowbase = (size_t)bh * MM + tile * 64;

    if (role == 0) {
        // ====================== flash producer ======================
        const int h = bh & (NH - 1);

        // Q fragments: slot(l,e) = Q[m0+(l&15)][ks*32 + (l>>4)*8 + e], split hi/lo bf16
        short8 qf[2][2];
        {
            const float* qr = q + (rowbase + w * 16 + lo) * DD + hi * 8;
#pragma unroll
            for (int ks = 0; ks < 2; ++ks) {
                float4 a = *(const float4*)(qr + ks * 32);
                float4 b = *(const float4*)(qr + ks * 32 + 4);
                float f[8] = {a.x, a.y, a.z, a.w, b.x, b.y, b.z, b.w};
                short8 qh, ql;
#pragma unroll
                for (int e = 0; e < 8; ++e) {
                    ushort_t hh = f2bf(f[e]);
                    qh[e] = (short)hh;
                    ql[e] = (short)f2bf(f[e] - bf2f(hh));
                }
                qf[ks][0] = qh;
                qf[ks][1] = ql;
            }
        }

        const ushort_t* KVb = wsKV + (size_t)h * (16 * 8192);

        auto STAGE = [&](int b, int c) {
            const char* src = (const char*)(KVb + (size_t)c * 8192) + w * 4096 + l * 16;
            char* dst = (char*)&kvbuf[b][0] + w * 4096;
#pragma unroll
            for (int j = 0; j < 4; ++j)
                __builtin_amdgcn_global_load_lds(
                    (const __attribute__((address_space(1))) void*)(src + j * 1024),
                    (__attribute__((address_space(3))) void*)(dst + j * 1024),
                    16, 0, 0);
        };

        f32x4 oacc[4] = {{0.f,0.f,0.f,0.f},{0.f,0.f,0.f,0.f},{0.f,0.f,0.f,0.f},{0.f,0.f,0.f,0.f}};
        float spart = 0.f;

        STAGE(0, 0);
        __syncthreads();

        for (int c = 0; c < 16; ++c) {
            const int cur = c & 1;
            if (c < 15) STAGE(cur ^ 1, c + 1);

            const ushort_t* Kc = &kvbuf[cur][0];
            const ushort_t* Vc = Kc + 4096;

            // ---- S^T chunk (log2e-scaled): p = c*64 + pb*16 + hi*4 + reg, m = lo ----
            f32x4 sacc[4] = {{0.f,0.f,0.f,0.f},{0.f,0.f,0.f,0.f},{0.f,0.f,0.f,0.f},{0.f,0.f,0.f,0.f}};
            __builtin_amdgcn_s_setprio(1);
#pragma unroll
            for (int pb = 0; pb < 4; ++pb) {
#pragma unroll
                for (int ks = 0; ks < 2; ++ks) {
                    short8 khi = *(const short8*)(Kc + (pb * 2 + ks) * 512 + l * 8);
                    sacc[pb] = MFMA(khi, qf[ks][0], sacc[pb]);
                    sacc[pb] = MFMA(khi, qf[ks][1], sacc[pb]);
                }
            }
            __builtin_amdgcn_s_setprio(0);

            // ---- P = exp2(sacc), split to bf16 frags, partial row-sum ----
            float ep[4][4];
#pragma unroll
            for (int pb = 0; pb < 4; ++pb)
#pragma unroll
                for (int r = 0; r < 4; ++r) {
                    float pv = EXP2(sacc[pb][r]);
                    ep[pb][r] = pv;
                    spart += pv;
                }

            short8 pf[2][2];
#pragma unroll
            for (int ks2 = 0; ks2 < 2; ++ks2) {
                short8 phi8, plo8;
#pragma unroll
                for (int e = 0; e < 8; ++e) {
                    float pv = ep[ks2 * 2 + (e >> 2)][e & 3];
                    ushort_t hh = f2bf(pv);
                    phi8[e] = (short)hh;
                    plo8[e] = (short)f2bf(pv - bf2f(hh));
                }
                pf[ks2][0] = phi8;
                pf[ks2][1] = plo8;
            }

            // ---- PV ----
            __builtin_amdgcn_s_setprio(1);
#pragma unroll
            for (int ks2 = 0; ks2 < 2; ++ks2) {
#pragma unroll
                for (int db = 0; db < 4; ++db) {
                    short8 vhi = *(const short8*)(Vc + (ks2 * 4 + db) * 512 + l * 8);
                    oacc[db] = MFMA(pf[ks2][0], vhi, oacc[db]);
                    oacc[db] = MFMA(pf[ks2][1], vhi, oacc[db]);
                }
            }
            __builtin_amdgcn_s_setprio(0);

            __syncthreads();   // buf[cur^1] staged; all waves done with buf[cur]
        }

        // ---- epilogue: sp + raw out (regular stores), fence, release flag ----
        spart += __shfl_xor(spart, 16);
        spart += __shfl_xor(spart, 32);
        if (hi == 0) ws_sp[(size_t)unit * 64 + w * 16 + lo] = spart;

#pragma unroll
        for (int reg = 0; reg < 4; ++reg) {
            const size_t ro = (rowbase + w * 16 + hi * 4 + reg) * DD + lo;
#pragma unroll
            for (int db = 0; db < 4; ++db)
                out[ro + db * 16] = oacc[db][reg];
        }

        __threadfence();
        __syncthreads();
        if (t == 0)
            __hip_atomic_store(&flags[unit], 1, __ATOMIC_RELEASE, __HIP_MEMORY_SCOPE_AGENT);
    } else {
        // ====================== norm consumer ======================
        // phase 1: stats for this unit's 64 attn rows (overlaps flash)
        for (int rr = 0; rr < 16; ++rr) {
            const int r = w * 16 + rr;
            const f32x4* arow = (const f32x4*)(attn + (rowbase + r) * SPAN);
            f32x4 av[4];
#pragma unroll
            for (int j = 0; j < 4; ++j) av[j] = arow[j * 64 + l];
            float sm = 0.f;
#pragma unroll
            for (int j = 0; j < 4; ++j)
#pragma unroll
                for (int e = 0; e < 4; ++e) sm += EXP2(av[j][e] * ATTN_SC);
#pragma unroll
            for (int s = 1; s < 64; s <<= 1) sm += __shfl_xor(sm, s);
            if (l == 0) sa[r] = sm;
        }
        __syncthreads();

        // phase 2: acquire this unit's pers results (producer never waits -> no deadlock)
        if (t == 0) {
            while (__hip_atomic_load(&flags[unit], __ATOMIC_ACQUIRE, __HIP_MEMORY_SCOPE_AGENT) == 0)
                __builtin_amdgcn_s_sleep(16);
        }
        __syncthreads();

        // phase 3: merged iZ
        if (t < 64) iZ[t] = 1.f / (sa[t] + ws_sp[(size_t)unit * 64 + t]);
        __syncthreads();

        // phase 4: normalize attn_out (L3-warm re-read) + rescale raw out
        for (int rr = 0; rr < 16; ++rr) {
            const int r = w * 16 + rr;
            const size_t row = rowbase + r;
            const float z = iZ[r];
            const f32x4* arow = (const f32x4*)(attn + row * SPAN);
            f32x4*       orow = (f32x4*)(attn_out + row * SPAN);
#pragma unroll
            for (int j = 0; j < 4; ++j) {
                f32x4 a = arow[j * 64 + l];
                f32x4 o;
#pragma unroll
                for (int e = 0; e < 4; ++e) o[e] = EXP2(a[e] * ATTN_SC) * z;
                __builtin_nontemporal_store(o, orow + j * 64 + l);
            }
            const float ov = out[row * DD + l];
            __builtin_nontemporal_store(ov * 32.f * z, &out[row * DD + l]);
        }
    }
}

// ---------------- fallback (fp32 VALU) if ws too small ----------------
__launch_bounds__(256)
__global__ void pm_fallback(const float* __restrict__ q,
                            const float* __restrict__ attn,
                            const float* __restrict__ key,
                            const float* __restrict__ val,
                            float* __restrict__ attn_out,
                            float* __restrict__ out)
{
    __shared__ float qs[64][68];
    __shared__ float ks[64][68];
    __shared__ float vs[64][DD];
    __shared__ float sc[64][66];
    __shared__ float rmax[64];
    __shared__ float rsum[64];

    const int t    = threadIdx.x;
    const int bh   = blockIdx.y;
    const int tile = blockIdx.x;
    const int h    = bh & (NH - 1);
    const int m0   = tile * 64;
    const int tr   = t >> 4;
    const int tc   = t & 15;
    const int r0   = tr * 4;
    const int c0   = tc * 4;
    const int lane = t & 63;
    const int wave = t >> 6;

    const size_t qbase = (size_t)bh * MM * DD + (size_t)m0 * DD;
    const size_t abase = (size_t)bh * MM * SPAN + (size_t)m0 * SPAN;
    const size_t kbase = (size_t)h * DD * PP;
    const size_t vbase = (size_t)h * PP * DD;

#pragma unroll
    for (int j = 0; j < 16; ++j) {
        int idx = j * 256 + t;
        int r = idx >> 6, d = idx & 63;
        qs[r][d] = q[qbase + (size_t)r * DD + d];
    }
    for (int rr = 0; rr < 16; ++rr) {
        int r = wave * 16 + rr;
        const float* arow = attn + abase + (size_t)r * SPAN;
        float av[16];
        float mx = -INFINITY;
#pragma unroll
        for (int j = 0; j < 16; ++j) { av[j] = arow[j * 64 + lane] * 0.125f; mx = fmaxf(mx, av[j]); }
#pragma unroll
        for (int s = 32; s; s >>= 1) mx = fmaxf(mx, __shfl_xor(mx, s));
        float sm = 0.f;
#pragma unroll
        for (int j = 0; j < 16; ++j) sm += __expf(av[j] - mx);
#pragma unroll
        for (int s = 32; s; s >>= 1) sm += __shfl_xor(sm, s);
        if (lane == 0) { rmax[r] = mx; rsum[r] = sm; }
    }
    __syncthreads();
    for (int p0 = 0; p0 < PP; p0 += 64) {
        if (p0) __syncthreads();
#pragma unroll
        for (int j = 0; j < 16; ++j) {
            int idx = j * 256 + t;
            int d = idx >> 6, pc = idx & 63;
            ks[pc][d] = key[kbase + (size_t)d * PP + p0 + pc];
        }
        __syncthreads();
        float acc[4][4] = {};
#pragma unroll
        for (int d0 = 0; d0 < DD; d0 += 4) {
            float4 q4[4], k4[4];
#pragma unroll
            for (int rr = 0; rr < 4; ++rr) q4[rr] = *(const float4*)&qs[r0 + rr][d0];
#pragma unroll
            for (int cc = 0; cc < 4; ++cc) k4[cc] = *(const float4*)&ks[c0 + cc][d0];
#pragma unroll
            for (int rr = 0; rr < 4; ++rr)
#pragma unroll
                for (int cc = 0; cc < 4; ++cc)
                    acc[rr][cc] += q4[rr].x * k4[cc].x + q4[rr].y * k4[cc].y
                                 + q4[rr].z * k4[cc].z + q4[rr].w * k4[cc].w;
        }
#pragma unroll
        for (int rr = 0; rr < 4; ++rr) {
            float mx = fmaxf(fmaxf(acc[rr][0], acc[rr][1]), fmaxf(acc[rr][2], acc[rr][3]));
#pragma unroll
            for (int s = 8; s; s >>= 1) mx = fmaxf(mx, __shfl_xor(mx, s));
            float sm = 0.f;
#pragma unroll
            for (int cc = 0; cc < 4; ++cc) sm += __expf(acc[rr][cc] - mx);
#pragma unroll
            for (int s = 8; s; s >>= 1) sm += __shfl_xor(sm, s);
            if (tc == 0) {
                int r = r0 + rr;
                float om = rmax[r], os = rsum[r];
                float nm = fmaxf(om, mx);
                rsum[r] = os * __expf(om - nm) + sm * __expf(mx - nm);
                rmax[r] = nm;
            }
        }
    }
    __syncthreads();
    for (int rr = 0; rr < 16; ++rr) {
        int r = wave * 16 + rr;
        float Mx = rmax[r];
        float iZv = 1.0f / rsum[r];
        const float* arow = attn + abase + (size_t)r * SPAN;
        float* orow = attn_out + abase + (size_t)r * SPAN;
#pragma unroll
        for (int j = 0; j < 16; ++j) {
            float a = arow[j * 64 + lane] * 0.125f;
            orow[j * 64 + lane] = __expf(a - Mx) * iZv;
        }
    }
    float acc2[4][4] = {};
    for (int p0 = 0; p0 < PP; p0 += 64) {
        __syncthreads();
#pragma unroll
        for (int j = 0; j < 16; ++j) {
            int idx = j * 256 + t;
            int d = idx >> 6, pc = idx & 63;
            ks[pc][d] = key[kbase + (size_t)d * PP + p0 + pc];
        }
#pragma unroll
        for (int j = 0; j < 16; ++j) {
            int idx = j * 256 + t;
            int pc = idx >> 6, d = idx & 63;
            vs[pc][d] = val[vbase + (size_t)(p0 + pc) * DD + d];
        }
        __syncthreads();
        float acc[4][4] = {};
#pragma unroll
        for (int d0 = 0; d0 < DD; d0 += 4) {
            float4 q4[4], k4[4];
#pragma unroll
            for (int rr = 0; rr < 4; ++rr) q4[rr] = *(const float4*)&qs[r0 + rr][d0];
#pragma unroll
            for (int cc = 0; cc < 4; ++cc) k4[cc] = *(const float4*)&ks[c0 + cc][d0];
#pragma unroll
            for (int rr = 0; rr < 4; ++rr)
#pragma unroll
                for (int cc = 0; cc < 4; ++cc)
                    acc[rr][cc] += q4[rr].x * k4[cc].x + q4[rr].y * k4[cc].y
                                 + q4[rr].z * k4[cc].z + q4[rr].w * k4[cc].w;
        }
#pragma unroll
        for (int rr = 0; rr < 4; ++rr) {
            float Mx = rmax[r0 + rr];
#pragma unroll
            for (int cc = 0; cc < 4; ++cc)
                sc[r0 + rr][c0 + cc] = __expf(acc[rr][cc] - Mx);
        }
        __syncthreads();
        for (int pc = 0; pc < 64; ++pc) {
            float4 v4 = *(const float4*)&vs[pc][tc * 4];
#pragma unroll
            for (int rr = 0; rr < 4; ++rr) {
                float pr = sc[r0 + rr][pc];
                acc2[rr][0] += pr * v4.x;
                acc2[rr][1] += pr * v4.y;
                acc2[rr][2] += pr * v4.z;
                acc2[rr][3] += pr * v4.w;
            }
        }
    }
#pragma unroll
    for (int rr = 0; rr < 4; ++rr) {
        int r = r0 + rr;
        float s = 32.0f / rsum[r];
        float4 o;
        o.x = acc2[rr][0] * s; o.y = acc2[rr][1] * s;
        o.z = acc2[rr][2] * s; o.w = acc2[rr][3] * s;
        *(float4*)&out[(size_t)bh * MM * DD + (size_t)(m0 + r) * DD + tc * 4] = o;
    }
}

extern "C" void kernel_launch(void* const* d_in, const int* in_sizes, int n_in,
                              void* d_out, int out_size, void* d_ws, size_t ws_size,
                              hipStream_t stream) {
    const float* q    = (const float*)d_in[0];
    const float* attn = (const float*)d_in[1];
    const float* key  = (const float*)d_in[2];
    const float* val  = (const float*)d_in[3];
    float* attn_out = (float*)d_out;
    float* out      = (float*)d_out + (size_t)BH * MM * SPAN;

    if (ws_size >= WS_NEED) {
        ushort_t* wsKV  = (ushort_t*)d_ws;
        float*    ws_sp = (float*)((char*)d_ws + WS_SP_OFF);
        int*      flags = (int*)((char*)d_ws + WS_FLAG_OFF);
        hipMemsetAsync(flags, 0, 512 * sizeof(int), stream);
        pm_pre <<<1024, 256, 0, stream>>>(key, val, wsKV);
        pm_pipe<<<1024, 256, 0, stream>>>(q, attn, wsKV, ws_sp, flags, attn_out, out);
    } else {
        dim3 grid(MM / 64, BH);
        pm_fallback<<<grid, 256, 0, stream>>>(q, attn, key, val, attn_out, out);
    }
}

// Round 11
// 75.376 us; speedup vs baseline: 2.4363x; 2.4363x over previous
//
#include <hip/hip_runtime.h>
#include <hip/hip_bf16.h>
#include <math.h>

#define BH   32
#define NH   16
#define MM   1024
#define DD   64
#define PP   1024
#define SPAN 1024

typedef unsigned short ushort_t;
typedef __attribute__((ext_vector_type(8))) short  short8;
typedef __attribute__((ext_vector_type(4))) float  f32x4;

#define MFMA(a,b,c) __builtin_amdgcn_mfma_f32_16x16x32_bf16(a,b,c,0,0,0)

#if __has_builtin(__builtin_amdgcn_exp2f)
#define EXP2(x) __builtin_amdgcn_exp2f(x)
#else
#define EXP2(x) __expf((x) * 0.6931471805599453f)
#endif

// exp(a*0.125) = exp2(a * 0.125*log2(e))
#define ATTN_SC 0.18033688011111603f
#define LOG2E   1.4426950408889634f

// ws layout (bytes):
//   [0, 4 MB)        K/V bf16 fragment blobs. Chunk blob (h,c) = 8192 ushorts (16 KB)
//   [4 MB, +128K)    per-row s_pers split 0
//   [4.125, +128K)   per-row s_pers split 1
//   [4.25 MB, +8 MB) o1: raw PV partial for split 1 (f32, [row][64])
#define WS_SP0_OFF (4194304ull)
#define WS_SP1_OFF (4325376ull)
#define WS_O1_OFF  (4456448ull)
#define WS_NEED    (12845056ull)

__device__ __forceinline__ ushort_t f2bf(float x) {
    __hip_bfloat16 b = __float2bfloat16(x);
    return __builtin_bit_cast(unsigned short, b);
}
__device__ __forceinline__ float bf2f(ushort_t u) {
    __hip_bfloat16 b = __builtin_bit_cast(__hip_bfloat16, u);
    return __bfloat162float(b);
}

// ---------------- pre-kernel: bf16 K/V fragment packing (K scaled by log2e) ----------------
__launch_bounds__(256)
__global__ void pm_pre(const float* __restrict__ key,
                       const float* __restrict__ val,
                       ushort_t* __restrict__ wsKV)
{
    int bi = blockIdx.x, t = threadIdx.x;
    if (bi < 512) {
        int id = bi * 256 + t;                 // 131072
        int l  = id & 63;
        int ks = (id >> 6) & 1;
        int pb = (id >> 7) & 3;
        int c  = (id >> 9) & 15;
        int h  = (id >> 13) & 15;
        int p     = c * 64 + pb * 16 + (l & 15);
        int dbase = ks * 32 + (l >> 4) * 8;
        size_t fo = (size_t)(h * 16 + c) * 8192 + (size_t)(pb * 2 + ks) * 512 + (size_t)l * 8;
#pragma unroll
        for (int e = 0; e < 8; ++e)
            wsKV[fo + e] = f2bf(key[(size_t)(h * 64 + dbase + e) * PP + p] * LOG2E);
    } else {
        int id = (bi - 512) * 256 + t;         // 131072
        int l   = id & 63;
        int db  = (id >> 6) & 3;
        int ks2 = (id >> 8) & 1;
        int c   = (id >> 9) & 15;
        int h   = (id >> 13) & 15;
        int d = db * 16 + (l & 15);
        size_t fo = (size_t)(h * 16 + c) * 8192 + 4096 + (size_t)(ks2 * 4 + db) * 512 + (size_t)l * 8;
#pragma unroll
        for (int e = 0; e < 8; ++e) {
            int p = c * 64 + ks2 * 32 + ((l >> 4) * 4) + (e & 3) + 16 * (e >> 2);
            wsKV[fo + e] = f2bf(val[(size_t)(h * PP + p) * DD + d]);
        }
    }
}

// ---------------- flash kernel: pure MFMA phase, p-split (s = bi&1 owns chunks s*8..s*8+7) ----------------
// bi%8 is tile-independent for fixed (bh,s) -> all 16 tiles of a (bh,s) share one XCD's L2.
__launch_bounds__(256)
__global__ void pm_flash(const float* __restrict__ q,
                         const ushort_t* __restrict__ wsKV,
                         float* __restrict__ ws_sp0,
                         float* __restrict__ ws_sp1,
                         float* __restrict__ o1,
                         float* __restrict__ out)
{
    __shared__ ushort_t kvbuf[2][8192];     // 2 x 16 KB double buffer

    const int t  = threadIdx.x;
    const int w  = t >> 6;
    const int l  = t & 63;
    const int bi = blockIdx.x;
    const int hi = l >> 4;
    const int lo = l & 15;

    const int s    = bi & 1;
    const int unit = bi >> 1;              // 0..511
    const int bh   = unit & 31;
    const int tile = unit >> 5;
    const int h    = bh & (NH - 1);
    const size_t rowbase = (size_t)bh * MM + tile * 64;

    // Q fragments: slot(l,e) = Q[m0+(l&15)][ks*32 + (l>>4)*8 + e], split hi/lo bf16
    short8 qf[2][2];
    {
        const float* qr = q + (rowbase + w * 16 + lo) * DD + hi * 8;
#pragma unroll
        for (int ks = 0; ks < 2; ++ks) {
            float4 a = *(const float4*)(qr + ks * 32);
            float4 b = *(const float4*)(qr + ks * 32 + 4);
            float f[8] = {a.x, a.y, a.z, a.w, b.x, b.y, b.z, b.w};
            short8 qh, ql;
#pragma unroll
            for (int e = 0; e < 8; ++e) {
                ushort_t hh = f2bf(f[e]);
                qh[e] = (short)hh;
                ql[e] = (short)f2bf(f[e] - bf2f(hh));
            }
            qf[ks][0] = qh;
            qf[ks][1] = ql;
        }
    }

    const ushort_t* KVb = wsKV + (size_t)h * (16 * 8192);

    auto STAGE = [&](int b, int c) {
        const char* src = (const char*)(KVb + (size_t)c * 8192) + w * 4096 + l * 16;
        char* dst = (char*)&kvbuf[b][0] + w * 4096;
#pragma unroll
        for (int j = 0; j < 4; ++j)
            __builtin_amdgcn_global_load_lds(
                (const __attribute__((address_space(1))) void*)(src + j * 1024),
                (__attribute__((address_space(3))) void*)(dst + j * 1024),
                16, 0, 0);
    };

    f32x4 oacc[4] = {{0.f,0.f,0.f,0.f},{0.f,0.f,0.f,0.f},{0.f,0.f,0.f,0.f},{0.f,0.f,0.f,0.f}};
    float spart = 0.f;

    STAGE(0, s * 8);
    __syncthreads();

    for (int cc = 0; cc < 8; ++cc) {
        const int cur = cc & 1;
        if (cc < 7) STAGE(cur ^ 1, s * 8 + cc + 1);

        const ushort_t* Kc = &kvbuf[cur][0];
        const ushort_t* Vc = Kc + 4096;

        // ---- S^T chunk (log2e-scaled): p = (s*8+cc)*64 + pb*16 + hi*4 + reg, m = lo ----
        f32x4 sacc[4] = {{0.f,0.f,0.f,0.f},{0.f,0.f,0.f,0.f},{0.f,0.f,0.f,0.f},{0.f,0.f,0.f,0.f}};
        __builtin_amdgcn_s_setprio(1);
#pragma unroll
        for (int pb = 0; pb < 4; ++pb) {
#pragma unroll
            for (int ks = 0; ks < 2; ++ks) {
                short8 khi = *(const short8*)(Kc + (pb * 2 + ks) * 512 + l * 8);
                sacc[pb] = MFMA(khi, qf[ks][0], sacc[pb]);
                sacc[pb] = MFMA(khi, qf[ks][1], sacc[pb]);
            }
        }
        __builtin_amdgcn_s_setprio(0);

        // ---- P = exp2(sacc), split to bf16 frags, partial row-sum ----
        float ep[4][4];
#pragma unroll
        for (int pb = 0; pb < 4; ++pb)
#pragma unroll
            for (int r = 0; r < 4; ++r) {
                float pv = EXP2(sacc[pb][r]);
                ep[pb][r] = pv;
                spart += pv;
            }

        short8 pf[2][2];
#pragma unroll
        for (int ks2 = 0; ks2 < 2; ++ks2) {
            short8 phi8, plo8;
#pragma unroll
            for (int e = 0; e < 8; ++e) {
                float pv = ep[ks2 * 2 + (e >> 2)][e & 3];
                ushort_t hh = f2bf(pv);
                phi8[e] = (short)hh;
                plo8[e] = (short)f2bf(pv - bf2f(hh));
            }
            pf[ks2][0] = phi8;
            pf[ks2][1] = plo8;
        }

        // ---- PV ----
        __builtin_amdgcn_s_setprio(1);
#pragma unroll
        for (int ks2 = 0; ks2 < 2; ++ks2) {
#pragma unroll
            for (int db = 0; db < 4; ++db) {
                short8 vhi = *(const short8*)(Vc + (ks2 * 4 + db) * 512 + l * 8);
                oacc[db] = MFMA(pf[ks2][0], vhi, oacc[db]);
                oacc[db] = MFMA(pf[ks2][1], vhi, oacc[db]);
            }
        }
        __builtin_amdgcn_s_setprio(0);

        __syncthreads();   // buf[cur^1] staged; all waves done with buf[cur]
    }

    // ---- epilogue: reduce partial pers sums, write sp[s] + raw partial accumulator ----
    spart += __shfl_xor(spart, 16);
    spart += __shfl_xor(spart, 32);
    float* spdst = s ? ws_sp1 : ws_sp0;
    if (hi == 0) spdst[rowbase + w * 16 + lo] = spart;

    float* odst = s ? o1 : out;
#pragma unroll
    for (int reg = 0; reg < 4; ++reg) {
        const size_t ro = (rowbase + w * 16 + hi * 4 + reg) * DD + lo;
#pragma unroll
        for (int db = 0; db < 4; ++db)
            __builtin_nontemporal_store(oacc[db][reg], &odst[ro + db * 16]);
    }
}

// ------- statsnorm: one wave per row; attn read ONCE; stats+normalize+out merge fused -------
__launch_bounds__(256)
__global__ void pm_norm(const float* __restrict__ attn,
                        const float* __restrict__ ws_sp0,
                        const float* __restrict__ ws_sp1,
                        const float* __restrict__ o1,
                        float* __restrict__ attn_out,
                        float* __restrict__ out)
{
    const int t = threadIdx.x;
    const int w = t >> 6;
    const int l = t & 63;
    const size_t row = (size_t)blockIdx.x * 4 + w;   // 0..32767

    // read row, exp2 in place, accumulate lane-partial sum
    const f32x4* arow = (const f32x4*)(attn + row * SPAN);
    f32x4 av[4];
#pragma unroll
    for (int j = 0; j < 4; ++j) av[j] = arow[j * 64 + l];

    float sm = 0.f;
#pragma unroll
    for (int j = 0; j < 4; ++j)
#pragma unroll
        for (int e = 0; e < 4; ++e) {
            av[j][e] = EXP2(av[j][e] * ATTN_SC);
            sm += av[j][e];
        }
#pragma unroll
    for (int s = 1; s < 64; s <<= 1) sm += __shfl_xor(sm, s);

    const float iZ = 1.f / (sm + ws_sp0[row] + ws_sp1[row]);

    f32x4* orow = (f32x4*)(attn_out + row * SPAN);
#pragma unroll
    for (int j = 0; j < 4; ++j)
        __builtin_nontemporal_store(av[j] * iZ, orow + j * 64 + l);

    const float ov0 = out[row * DD + l];
    const float ov1 = o1[row * DD + l];
    __builtin_nontemporal_store((ov0 + ov1) * 32.f * iZ, &out[row * DD + l]);
}

// ---------------- fallback (fp32 VALU) if ws too small ----------------
__launch_bounds__(256)
__global__ void pm_fallback(const float* __restrict__ q,
                            const float* __restrict__ attn,
                            const float* __restrict__ key,
                            const float* __restrict__ val,
                            float* __restrict__ attn_out,
                            float* __restrict__ out)
{
    __shared__ float qs[64][68];
    __shared__ float ks[64][68];
    __shared__ float vs[64][DD];
    __shared__ float sc[64][66];
    __shared__ float rmax[64];
    __shared__ float rsum[64];

    const int t    = threadIdx.x;
    const int bh   = blockIdx.y;
    const int tile = blockIdx.x;
    const int h    = bh & (NH - 1);
    const int m0   = tile * 64;
    const int tr   = t >> 4;
    const int tc   = t & 15;
    const int r0   = tr * 4;
    const int c0   = tc * 4;
    const int lane = t & 63;
    const int wave = t >> 6;

    const size_t qbase = (size_t)bh * MM * DD + (size_t)m0 * DD;
    const size_t abase = (size_t)bh * MM * SPAN + (size_t)m0 * SPAN;
    const size_t kbase = (size_t)h * DD * PP;
    const size_t vbase = (size_t)h * PP * DD;

#pragma unroll
    for (int j = 0; j < 16; ++j) {
        int idx = j * 256 + t;
        int r = idx >> 6, d = idx & 63;
        qs[r][d] = q[qbase + (size_t)r * DD + d];
    }
    for (int rr = 0; rr < 16; ++rr) {
        int r = wave * 16 + rr;
        const float* arow = attn + abase + (size_t)r * SPAN;
        float av[16];
        float mx = -INFINITY;
#pragma unroll
        for (int j = 0; j < 16; ++j) { av[j] = arow[j * 64 + lane] * 0.125f; mx = fmaxf(mx, av[j]); }
#pragma unroll
        for (int s = 32; s; s >>= 1) mx = fmaxf(mx, __shfl_xor(mx, s));
        float sm = 0.f;
#pragma unroll
        for (int j = 0; j < 16; ++j) sm += __expf(av[j] - mx);
#pragma unroll
        for (int s = 32; s; s >>= 1) sm += __shfl_xor(sm, s);
        if (lane == 0) { rmax[r] = mx; rsum[r] = sm; }
    }
    __syncthreads();
    for (int p0 = 0; p0 < PP; p0 += 64) {
        if (p0) __syncthreads();
#pragma unroll
        for (int j = 0; j < 16; ++j) {
            int idx = j * 256 + t;
            int d = idx >> 6, pc = idx & 63;
            ks[pc][d] = key[kbase + (size_t)d * PP + p0 + pc];
        }
        __syncthreads();
        float acc[4][4] = {};
#pragma unroll
        for (int d0 = 0; d0 < DD; d0 += 4) {
            float4 q4[4], k4[4];
#pragma unroll
            for (int rr = 0; rr < 4; ++rr) q4[rr] = *(const float4*)&qs[r0 + rr][d0];
#pragma unroll
            for (int cc = 0; cc < 4; ++cc) k4[cc] = *(const float4*)&ks[c0 + cc][d0];
#pragma unroll
            for (int rr = 0; rr < 4; ++rr)
#pragma unroll
                for (int cc = 0; cc < 4; ++cc)
                    acc[rr][cc] += q4[rr].x * k4[cc].x + q4[rr].y * k4[cc].y
                                 + q4[rr].z * k4[cc].z + q4[rr].w * k4[cc].w;
        }
#pragma unroll
        for (int rr = 0; rr < 4; ++rr) {
            float mx = fmaxf(fmaxf(acc[rr][0], acc[rr][1]), fmaxf(acc[rr][2], acc[rr][3]));
#pragma unroll
            for (int s = 8; s; s >>= 1) mx = fmaxf(mx, __shfl_xor(mx, s));
            float sm = 0.f;
#pragma unroll
            for (int cc = 0; cc < 4; ++cc) sm += __expf(acc[rr][cc] - mx);
#pragma unroll
            for (int s = 8; s; s >>= 1) sm += __shfl_xor(sm, s);
            if (tc == 0) {
                int r = r0 + rr;
                float om = rmax[r], os = rsum[r];
                float nm = fmaxf(om, mx);
                rsum[r] = os * __expf(om - nm) + sm * __expf(mx - nm);
                rmax[r] = nm;
            }
        }
    }
    __syncthreads();
    for (int rr = 0; rr < 16; ++rr) {
        int r = wave * 16 + rr;
        float Mx = rmax[r];
        float iZv = 1.0f / rsum[r];
        const float* arow = attn + abase + (size_t)r * SPAN;
        float* orow = attn_out + abase + (size_t)r * SPAN;
#pragma unroll
        for (int j = 0; j < 16; ++j) {
            float a = arow[j * 64 + lane] * 0.125f;
            orow[j * 64 + lane] = __expf(a - Mx) * iZv;
        }
    }
    float acc2[4][4] = {};
    for (int p0 = 0; p0 < PP; p0 += 64) {
        __syncthreads();
#pragma unroll
        for (int j = 0; j < 16; ++j) {
            int idx = j * 256 + t;
            int d = idx >> 6, pc = idx & 63;
            ks[pc][d] = key[kbase + (size_t)d * PP + p0 + pc];
        }
#pragma unroll
        for (int j = 0; j < 16; ++j) {
            int idx = j * 256 + t;
            int pc = idx >> 6, d = idx & 63;
            vs[pc][d] = val[vbase + (size_t)(p0 + pc) * DD + d];
        }
        __syncthreads();
        float acc[4][4] = {};
#pragma unroll
        for (int d0 = 0; d0 < DD; d0 += 4) {
            float4 q4[4], k4[4];
#pragma unroll
            for (int rr = 0; rr < 4; ++rr) q4[rr] = *(const float4*)&qs[r0 + rr][d0];
#pragma unroll
            for (int cc = 0; cc < 4; ++cc) k4[cc] = *(const float4*)&ks[c0 + cc][d0];
#pragma unroll
            for (int rr = 0; rr < 4; ++rr)
#pragma unroll
                for (int cc = 0; cc < 4; ++cc)
                    acc[rr][cc] += q4[rr].x * k4[cc].x + q4[rr].y * k4[cc].y
                                 + q4[rr].z * k4[cc].z + q4[rr].w * k4[cc].w;
        }
#pragma unroll
        for (int rr = 0; rr < 4; ++rr) {
            float Mx = rmax[r0 + rr];
#pragma unroll
            for (int cc = 0; cc < 4; ++cc)
                sc[r0 + rr][c0 + cc] = __expf(acc[rr][cc] - Mx);
        }
        __syncthreads();
        for (int pc = 0; pc < 64; ++pc) {
            float4 v4 = *(const float4*)&vs[pc][tc * 4];
#pragma unroll
            for (int rr = 0; rr < 4; ++rr) {
                float pr = sc[r0 + rr][pc];
                acc2[rr][0] += pr * v4.x;
                acc2[rr][1] += pr * v4.y;
                acc2[rr][2] += pr * v4.z;
                acc2[rr][3] += pr * v4.w;
            }
        }
    }
#pragma unroll
    for (int rr = 0; rr < 4; ++rr) {
        int r = r0 + rr;
        float s = 32.0f / rsum[r];
        float4 o;
        o.x = acc2[rr][0] * s; o.y = acc2[rr][1] * s;
        o.z = acc2[rr][2] * s; o.w = acc2[rr][3] * s;
        *(float4*)&out[(size_t)bh * MM * DD + (size_t)(m0 + r) * DD + tc * 4] = o;
    }
}

extern "C" void kernel_launch(void* const* d_in, const int* in_sizes, int n_in,
                              void* d_out, int out_size, void* d_ws, size_t ws_size,
                              hipStream_t stream) {
    const float* q    = (const float*)d_in[0];
    const float* attn = (const float*)d_in[1];
    const float* key  = (const float*)d_in[2];
    const float* val  = (const float*)d_in[3];
    float* attn_out = (float*)d_out;
    float* out      = (float*)d_out + (size_t)BH * MM * SPAN;

    if (ws_size >= WS_NEED) {
        ushort_t* wsKV   = (ushort_t*)d_ws;
        float*    ws_sp0 = (float*)((char*)d_ws + WS_SP0_OFF);
        float*    ws_sp1 = (float*)((char*)d_ws + WS_SP1_OFF);
        float*    o1     = (float*)((char*)d_ws + WS_O1_OFF);
        pm_pre  <<<1024, 256, 0, stream>>>(key, val, wsKV);
        pm_flash<<<1024, 256, 0, stream>>>(q, wsKV, ws_sp0, ws_sp1, o1, out);
        pm_norm <<<8192, 256, 0, stream>>>(attn, ws_sp0, ws_sp1, o1, attn_out, out);
    } else {
        dim3 grid(MM / 64, BH);
        pm_fallback<<<grid, 256, 0, stream>>>(q, attn, key, val, attn_out, out);
    }
}